// Round 5
// baseline (1882.318 us; speedup 1.0000x reference)
//
#include <hip/hip_runtime.h>

// mRNN: h_{t+1} = h + 0.1*(-h + relu(h) @ W_eff^T + tonic + ext) + 0.01*noise
// out[b,t] = readout over relu(h[500:600]) via out_w
//
// R4 lesson: LDS->L2 W-stream move changed nothing -> latency/barrier-bound,
// not pipe-bound. 3 serial costs: (1) __syncthreads drains vmcnt(0) -> HBM
// noise latency (~900cy) paid every step; (2) readout shuffle chain between
// barriers; (3) only 2 waves/SIMD.
// R5: 16 waves x 1024 thr (4 waves/SIMD; 128-VGPR cap == hardware optimum),
// one row/lane, W nearly all in regs (<=20 quads/lane, rest L2-streamed).
// Raw s_barrier + explicit lgkmcnt-only waits -> noise/inp prefetched one
// full step ahead (never drained). Readout done by the near-idle iti wave
// from the r-buffer (one step delayed), off the critical path.

typedef _Float16 f16;
typedef _Float16 h2 __attribute__((ext_vector_type(2)));

__device__ __forceinline__ unsigned pack_f16x2(float a, float b){
  union { f16 h[2]; unsigned u; } cv;
  cv.h[0] = (f16)a; cv.h[1] = (f16)b;
  return cv.u;
}

// acc += w.lo*r.lo + w.hi*r.hi  (f16 inputs, f32 accumulate)
__device__ __forceinline__ void mac2(unsigned w, unsigned r, float& acc){
#if __has_builtin(__builtin_amdgcn_fdot2)
  acc = __builtin_amdgcn_fdot2(__builtin_bit_cast(h2, w), __builtin_bit_cast(h2, r), acc, false);
#else
  union U { unsigned u; h2 v; } cw, cr;
  cw.u = w; cr.u = r;
  acc += (float)cw.v.x * (float)cr.v.x;
  acc += (float)cw.v.y * (float)cr.v.y;
#endif
}

__device__ __forceinline__ void wait_lgkm0(){
  asm volatile("s_waitcnt lgkmcnt(0)" ::: "memory");
}
__device__ __forceinline__ void barrier_raw(){
  __builtin_amdgcn_s_barrier();
  asm volatile("" ::: "memory");
}

// ---------------- block tables (prep; layout identical to verified R3/R4) ----------------
namespace tb {
constexpr int qoffs[12] = {0,1300,2600,3600,4900,5600,6900,7600,8900,10200,11500,12800};
constexpr int Qs [11] = {13,13,10,13, 7,13, 7,13,13,13,13};
constexpr int tgt[11] = {0,0,0,0,100,200,300,300,400,500,500};
constexpr int slo[11] = {0,400,500,600, 50,100,  0,200,300,400,500};
constexpr int shi[11] = {100,500,570,700,100,200, 50,300,400,500,600};
constexpr int rpb[11] = {0,200,248,300, 24, 48,  0,100,148,200,248};
}

__device__ __forceinline__ float wval(const float* __restrict__ Wrec,
    const float* __restrict__ Wm, const float* __restrict__ Ws,
    const float* __restrict__ Wf, int i, int j, int lo, int hi){
  if (j < lo || j >= hi) return 0.f;
  int idx = i*700 + j;
  return fmaxf(Wrec[idx], 0.f)*Wm[idx]*Ws[idx] + Wf[idx];
}

__global__ void prep_kernel(const float* __restrict__ Wrec, const float* __restrict__ Wm,
                            const float* __restrict__ Ws, const float* __restrict__ Wf,
                            uint4* __restrict__ Wp){
  int s = blockIdx.x*blockDim.x + threadIdx.x;
  if (s >= 12800) return;
  int blk = 0;
  while (s >= tb::qoffs[blk+1]) ++blk;
  int rel = s - tb::qoffs[blk];
  int Q = tb::Qs[blk];
  int half, q, lane;
  if (rel < Q*64){ half = 0; q = rel >> 6; lane = rel & 63; }
  else { int r2 = rel - Q*64; half = 1; q = r2/36; lane = r2 - q*36; }
  int i = tb::tgt[blk] + half*64 + lane;
  unsigned pk[4];
  #pragma unroll
  for (int p = 0; p < 4; ++p){
    int pr = tb::rpb[blk] + q*4 + p;
    float v0 = wval(Wrec,Wm,Ws,Wf, i, 2*pr,   tb::slo[blk], tb::shi[blk]);
    float v1 = wval(Wrec,Wm,Ws,Wf, i, 2*pr+1, tb::slo[blk], tb::shi[blk]);
    pk[p] = pack_f16x2(v0, v1);
  }
  Wp[s] = make_uint4(pk[0], pk[1], pk[2], pk[3]);
}

// ---------------- 16-wave config: one target row per lane ----------------
// w0/w1: str rows (halves), part1 = str<-str + str<-thal; read partial
// w2/w3: str part2 = str<-alm + str<-iti; write partial; own no rows
// w4/w5: snr; w6/w7: alm; w8/w9: stn; w10/w11: thal; w12/w13: gpe
// w14/w15: iti (no dots); w15 also does the readout (one step delayed)
namespace cfg {
constexpr int  NL [16] = {64,36,64,36,64,36,64,36,64,36,64,36,64,36,64,36};
constexpr int  IB [16] = {0,64,0,64,300,364,500,564,200,264,400,464,100,164,600,664};
constexpr bool HR [16] = {true,true,false,false,true,true,true,true,true,true,true,true,true,true,true,true};
// reg block 1 (fully register-resident)
constexpr int  Q1 [16] = {13,13,10,10,7,7,13,13,13,13,13,13,7,7,0,0};
constexpr int  G1 [16] = {0,832,2600,3240,6900,7348,10200,11032,5600,6432,8900,9732,4900,5348,0,0};
constexpr int  RP1[16] = {0,0,248,248,0,0,200,200,48,48,148,148,24,24,0,0};
// reg block 2 (register-resident prefix of second block)
constexpr int  Q2R[16] = {5,5,8,8,13,13,5,5,0,0,0,0,0,0,0,0};
constexpr int  G2 [16] = {1300,2132,3600,4432,7600,8432,11500,12332,0,0,0,0,0,0,0,0};
constexpr int  RP2[16] = {200,200,300,300,100,100,248,248,0,0,0,0,0,0,0,0};
// streamed remainder of block 2 (from L2-resident Wp)
constexpr int  QS [16] = {8,8,5,5,0,0,8,8,0,0,0,0,0,0,0,0};
constexpr int  SB [16] = {1620,2312,4112,4720,0,0,11820,12512,0,0,0,0,0,0,0,0};
constexpr int  RPS[16] = {220,220,332,332,0,0,268,268,0,0,0,0,0,0,0,0};
// partial handoff
constexpr bool PW [16] = {false,false,true,true,false,false,false,false,false,false,false,false,false,false,false,false};
constexpr int  PWB[16] = {0,0,0,64,0,0,0,0,0,0,0,0,0,0,0,0};
constexpr bool PR [16] = {true,true,false,false,false,false,false,false,false,false,false,false,false,false,false,false};
constexpr int  PRB[16] = {0,64,0,0,0,0,0,0,0,0,0,0,0,0,0,0};
// iti external input / readout duty
constexpr bool ITI[16] = {false,false,false,false,false,false,false,false,false,false,false,false,false,false,true,true};
constexpr bool RD [16] = {false,false,false,false,false,false,false,false,false,false,false,false,false,false,false,true};
}

template<int Q>
__device__ __forceinline__ float dot_reg(const uint4 (&w)[Q], const f16* rc, int rpb){
  float ax = 0.f, ay = 0.f, az = 0.f, aw = 0.f;
  const uint4* rq = (const uint4*)(rc + 2*rpb);
  #pragma unroll
  for (int q = 0; q < Q; ++q){
    uint4 r = rq[q];                 // uniform-address LDS broadcast (b128)
    mac2(w[q].x, r.x, ax);
    mac2(w[q].y, r.y, ay);
    mac2(w[q].z, r.z, az);
    mac2(w[q].w, r.w, aw);
  }
  return (ax + ay) + (az + aw);
}

template<int Q, int NLANE>
__device__ __forceinline__ float dot_glb(const uint4* __restrict__ wg, int lane,
                                         const f16* rc, int rpb){
  float ax = 0.f, ay = 0.f, az = 0.f, aw = 0.f;
  const uint4* rq = (const uint4*)(rc + 2*rpb);
  #pragma unroll
  for (int q = 0; q < Q; ++q){
    uint4 w = wg[q*NLANE + lane];    // L2-resident global load (VMEM pipe)
    uint4 r = rq[q];
    mac2(w.x, r.x, ax);
    mac2(w.y, r.y, ay);
    mac2(w.z, r.z, az);
    mac2(w.w, r.w, aw);
  }
  return (ax + ay) + (az + aw);
}

template<int WID>
__device__ __forceinline__ void wave_loop(const float* __restrict__ inp,
    const float* __restrict__ noise, const float* __restrict__ tonic,
    const float* __restrict__ outw, const uint4* __restrict__ Wp,
    float* __restrict__ out, int b, int lane,
    f16 (*rbuf)[704], float* part_str){
  using namespace cfg;
  constexpr int nl = NL[WID];
  constexpr int q1 = Q1[WID], q2r = Q2R[WID], qs = QS[WID];
  const bool act = lane < nl;

  // --- register-resident W ---
  uint4 w1r[(q1 > 0) ? q1 : 1], w2r[(q2r > 0) ? q2r : 1];
  if (act){
    if constexpr (q1 > 0){
      #pragma unroll
      for (int q = 0; q < q1; ++q) w1r[q] = Wp[G1[WID] + q*nl + lane];
    }
    if constexpr (q2r > 0){
      #pragma unroll
      for (int q = 0; q < q2r; ++q) w2r[q] = Wp[G2[WID] + q*nl + lane];
    }
  }
  float ton = 0.f;
  if (HR[WID] && act) ton = tonic[IB[WID] + lane];
  float ow0 = 0.f, ow1 = 0.f;
  if constexpr (RD[WID]){
    if (lane < 50){ ow0 = outw[2*lane]; ow1 = outw[2*lane + 1]; }
  }

  // --- prefetch t=0 externals (consumed in phase B of step 0) ---
  float nCur = 0.f, xCur = 0.f;
  if (HR[WID] && act){
    nCur = noise[(size_t)b*700000 + IB[WID] + lane];
    if constexpr (ITI[WID]) xCur = inp[(size_t)b*100000 + (IB[WID] - 600) + lane];
  }

  float h = 0.f;
  for (int t = 0; t < 1000; ++t){
    const f16* rc = rbuf[t & 1];
    f16* rn = rbuf[(t + 1) & 1];
    // --- issue next-step external loads (land ~1 full step later) ---
    const int tn = (t < 999) ? (t + 1) : 999;
    float nNxt = 0.f, xNxt = 0.f;
    if (HR[WID] && act){
      nNxt = noise[((size_t)b*1000 + tn)*700 + IB[WID] + lane];
      if constexpr (ITI[WID]) xNxt = inp[((size_t)b*1000 + tn)*100 + (IB[WID] - 600) + lane];
    }
    // ---- phase A: dots from r_cur ----
    float a = 0.f;
    if (act){
      if constexpr (q1 > 0)  a += dot_reg<q1>(w1r, rc, RP1[WID]);
      if constexpr (q2r > 0) a += dot_reg<q2r>(w2r, rc, RP2[WID]);
      if constexpr (qs > 0)  a += dot_glb<qs, nl>(Wp + SB[WID], lane, rc, RPS[WID]);
    }
    if constexpr (PW[WID]) { if (act) part_str[PWB[WID] + lane] = a; }
    if constexpr (RD[WID]){
      // readout of out[b,t-1] from rc = relu(h_t), off the critical path
      if (t > 0){
        float op = 0.f;
        if (lane < 50){
          unsigned v = ((const unsigned*)(rc + 500))[lane];
          union { unsigned u; h2 h; } cv; cv.u = v;
          op = (float)cv.h.x * ow0 + (float)cv.h.y * ow1;
        }
        #pragma unroll
        for (int d = 32; d > 0; d >>= 1) op += __shfl_xor(op, d);
        if (lane == 0) out[(size_t)b*1000 + (t - 1)] = op;
      }
    }
    wait_lgkm0();      // own ds ops (partial write) complete; NO vmcnt drain
    barrier_raw();     // barrier 1: partials visible
    // ---- phase B: h update, write r_next ----
    if (HR[WID] && act){
      float d = a + ton;
      if constexpr (PR[WID]) d += part_str[PRB[WID] + lane];
      if constexpr (ITI[WID]) d += xCur + 0.01f*nCur;
      h = h + 0.1f*(-h + d) + 0.01f*nCur;
      rn[IB[WID] + lane] = (f16)fmaxf(h, 0.f);
    }
    wait_lgkm0();      // rn writes complete
    barrier_raw();     // barrier 2: r_next visible
    nCur = nNxt; xCur = xNxt;
  }
  if constexpr (RD[WID]){
    // final readout: rbuf[0] = relu(h_1000) -> out[b,999]
    const f16* rc = rbuf[0];
    float op = 0.f;
    if (lane < 50){
      unsigned v = ((const unsigned*)(rc + 500))[lane];
      union { unsigned u; h2 h; } cv; cv.u = v;
      op = (float)cv.h.x * ow0 + (float)cv.h.y * ow1;
    }
    #pragma unroll
    for (int d = 32; d > 0; d >>= 1) op += __shfl_xor(op, d);
    if (lane == 0) out[(size_t)b*1000 + 999] = op;
  }
}

__global__ __launch_bounds__(1024)
void rnn_kernel(const float* __restrict__ inp, const float* __restrict__ noise,
                const float* __restrict__ tonic, const float* __restrict__ outw,
                const uint4* __restrict__ Wp, float* __restrict__ out){
  __shared__ __align__(16) f16 rbuf[2][704];
  __shared__ float part_str[100];
  const int tid = threadIdx.x;
  for (int k = tid; k < 704; k += 1024){ rbuf[0][k] = (f16)0.f; rbuf[1][k] = (f16)0.f; }
  __syncthreads();
  const int wid = tid >> 6, lane = tid & 63;
  const int b = blockIdx.x;
  switch (wid){
    case 0:  wave_loop<0>(inp,noise,tonic,outw,Wp,out,b,lane,rbuf,part_str); break;
    case 1:  wave_loop<1>(inp,noise,tonic,outw,Wp,out,b,lane,rbuf,part_str); break;
    case 2:  wave_loop<2>(inp,noise,tonic,outw,Wp,out,b,lane,rbuf,part_str); break;
    case 3:  wave_loop<3>(inp,noise,tonic,outw,Wp,out,b,lane,rbuf,part_str); break;
    case 4:  wave_loop<4>(inp,noise,tonic,outw,Wp,out,b,lane,rbuf,part_str); break;
    case 5:  wave_loop<5>(inp,noise,tonic,outw,Wp,out,b,lane,rbuf,part_str); break;
    case 6:  wave_loop<6>(inp,noise,tonic,outw,Wp,out,b,lane,rbuf,part_str); break;
    case 7:  wave_loop<7>(inp,noise,tonic,outw,Wp,out,b,lane,rbuf,part_str); break;
    case 8:  wave_loop<8>(inp,noise,tonic,outw,Wp,out,b,lane,rbuf,part_str); break;
    case 9:  wave_loop<9>(inp,noise,tonic,outw,Wp,out,b,lane,rbuf,part_str); break;
    case 10: wave_loop<10>(inp,noise,tonic,outw,Wp,out,b,lane,rbuf,part_str); break;
    case 11: wave_loop<11>(inp,noise,tonic,outw,Wp,out,b,lane,rbuf,part_str); break;
    case 12: wave_loop<12>(inp,noise,tonic,outw,Wp,out,b,lane,rbuf,part_str); break;
    case 13: wave_loop<13>(inp,noise,tonic,outw,Wp,out,b,lane,rbuf,part_str); break;
    case 14: wave_loop<14>(inp,noise,tonic,outw,Wp,out,b,lane,rbuf,part_str); break;
    default: wave_loop<15>(inp,noise,tonic,outw,Wp,out,b,lane,rbuf,part_str); break;
  }
}

extern "C" void kernel_launch(void* const* d_in, const int* in_sizes, int n_in,
                              void* d_out, int out_size, void* d_ws, size_t ws_size,
                              hipStream_t stream){
  const float* inp   = (const float*)d_in[0];
  const float* noise = (const float*)d_in[1];
  const float* Wrec  = (const float*)d_in[2];
  const float* Wmask = (const float*)d_in[3];
  const float* Wsign = (const float*)d_in[4];
  const float* Wfix  = (const float*)d_in[5];
  const float* tonic = (const float*)d_in[6];
  const float* outw  = (const float*)d_in[7];
  float* out = (float*)d_out;
  uint4* Wp = (uint4*)d_ws;    // 12800 * 16B = 204.8 KB packed weights

  prep_kernel<<<50, 256, 0, stream>>>(Wrec, Wmask, Wsign, Wfix, Wp);
  rnn_kernel<<<128, 1024, 0, stream>>>(inp, noise, tonic, outw, Wp, out);
}